// Round 8
// baseline (252.306 us; speedup 1.0000x reference)
//
#include <hip/hip_runtime.h>
#include <hip/hip_bf16.h>
#include <math.h>

// B=4, N=2048, C=384, H=8, HD=48, T=8192. scale=1/sqrt(48). RoPE base 100.

typedef __attribute__((ext_vector_type(8))) short bf16x8;
typedef __attribute__((ext_vector_type(4))) float f32x4;
typedef __attribute__((ext_vector_type(4))) short s16x4;

// RNE bf16 (scalar, 3 ops)
__device__ inline short f2bf(float f) {
    unsigned u = __float_as_uint(f);
    u += 0x7fffu + ((u >> 16) & 1u);
    return (short)(u >> 16);
}
// HW packed RNE cvt (1 op): bf16(a) | bf16(b)<<16
__device__ inline unsigned pk_bf16(float a, float b) {
    __hip_bfloat162 h = __float22bfloat162_rn(make_float2(a, b));
    return *(reinterpret_cast<unsigned*>(&h));
}
// truncation packs (for hi/lo splits; remainder carried exactly in lo)
__device__ inline unsigned pk2(float lo, float hi) {
    return (__float_as_uint(lo) >> 16) | (__float_as_uint(hi) & 0xffff0000u);
}
__device__ inline float bflo(unsigned u) { return __uint_as_float(u << 16); }
__device__ inline float bfhi(unsigned u) { return __uint_as_float(u & 0xffff0000u); }
__device__ inline float exp2f_fast(float x) {
#if __has_builtin(__builtin_amdgcn_exp2f)
    return __builtin_amdgcn_exp2f(x);
#else
    return exp2f(x);
#endif
}
__device__ inline float ffract(float x) {
    float r;
    asm("v_fract_f32 %0, %1" : "=v"(r) : "v"(x));
    return r;
}
__device__ inline float fsin(float x) {   // x in revolutions, pre-reduced
    float r;
    asm("v_sin_f32 %0, %1\n\ts_nop 1" : "=v"(r) : "v"(x));
    return r;
}
__device__ inline float fcos(float x) {
    float r;
    asm("v_cos_f32 %0, %1\n\ts_nop 1" : "=v"(r) : "v"(x));
    return r;
}
__device__ inline int div48(int c) { return (c * 683) >> 15; }

// ---------------------------------------------------------------------------
// Weights fp32 -> hi/lo bf16 planes in MFMA B-FRAGMENT-MAJOR order:
//   Wf[z][tile=c>>4][ks=k>>5][lane=((k>>3)&3)*16 + (c&15)][j=k&7]
// so a wave's B fragment for (tile,ks) is ONE contiguous 1KB load.
// Wq,Wk,Wv,Wo concatenated (147456 shorts each).
// ---------------------------------------------------------------------------
__global__ __launch_bounds__(256)
void cvt_w(const float* __restrict__ w0, const float* __restrict__ w1,
           const float* __restrict__ w2, const float* __restrict__ w3,
           short* __restrict__ Wh, short* __restrict__ Wl)
{
    const float* s = blockIdx.y == 0 ? w0 : blockIdx.y == 1 ? w1
                   : blockIdx.y == 2 ? w2 : w3;
    const size_t i = (size_t)(blockIdx.x * 256 + threadIdx.x) * 4;
    const int c = (int)(i / 384);        // out-feature row
    const int k = (int)(i % 384);        // k%4==0 -> all 4 elems same quad/j-run
    const float4 x = *(const float4*)(s + i);
    const unsigned h01 = pk2(x.x, x.y);
    const unsigned h23 = pk2(x.z, x.w);
    const unsigned l01 = pk2(x.x - bflo(h01), x.y - bfhi(h01));
    const unsigned l23 = pk2(x.z - bflo(h23), x.w - bfhi(h23));
    // fragment-major dest (j = k&7 in {0,4}: 4 consecutive shorts = 8B store)
    const size_t off =
        ((((size_t)blockIdx.y * 24 + (c >> 4)) * 12 + (k >> 5)) * 64
         + ((k >> 3) & 3) * 16 + (c & 15)) * 8 + (k & 7);
    uint2 hv; hv.x = h01; hv.y = h23;
    uint2 lv; lv.x = l01; lv.y = l23;
    *(uint2*)(Wh + off) = hv;
    *(uint2*)(Wl + off) = lv;
}

// ---------------------------------------------------------------------------
// Fused QKV projection, 3-term split-bf16 MFMA. LDS-free, fragment-major W,
// zero barriers (R12-proven core). R16: occupancy fix — block tile shrunk
// 64m -> 32m (wave = 32m x 32n, acc[2][2]); grid 1152 -> 2304 blocks
// (~8 blocks/CU vs 4.5). All 4 waves share the block's 32 A rows (L1-hit);
// W L2 traffic doubles (~8 TB/s effective, well under the 34.5 ceiling).
// Epilogues write FRAGMENT-MAJOR packed buffers (see attn).
// q pre-scaled by s2 = scale*log2(e) so attn exp2 takes raw S.
// ---------------------------------------------------------------------------
__global__ __launch_bounds__(256, 6)
void gemm_qkv(const float* __restrict__ q_in, const float* __restrict__ k_in,
              const float* __restrict__ v_in,
              const short* __restrict__ Whp, const short* __restrict__ Wlp,
              const float* __restrict__ bq, const float* __restrict__ bk,
              const float* __restrict__ bv,
              const int* __restrict__ qpos, const int* __restrict__ kpos,
              short* __restrict__ qp0, short* __restrict__ qtb,
              short* __restrict__ kp0, short* __restrict__ ktb,
              short* __restrict__ vp)
{
    const int z = blockIdx.z;
    const float* A = z == 0 ? q_in : z == 1 ? k_in : v_in;
    const float* bias = z == 0 ? bq : z == 1 ? bk : bv;

    const int tid = threadIdx.x;
    const int wv = tid >> 6, lane = tid & 63;
    const int l15 = lane & 15, quad = lane >> 4;
    const int mb = blockIdx.x * 32;
    const int nbl = wv * 32;
    const int n0 = blockIdx.y * 128;

    // fragment-major W base for this wave's 2 n-tiles
    const int tbase = blockIdx.y * 8 + wv * 2 + z * 24;
    const short* wfh = Whp + ((size_t)tbase * 12 * 64 + lane) * 8;
    const short* wfl = Wlp + ((size_t)tbase * 12 * 64 + lane) * 8;

    f32x4 acc[2][2] = {};
    const float* a0 = A + (size_t)(mb + l15) * 384 + quad * 8;

    for (int ks = 0; ks < 12; ++ks) {
        const int o = ks * 32;
        bf16x8 ah[2], al[2];
        #pragma unroll
        for (int mt = 0; mt < 2; ++mt) {
            const float4 x0 = *(const float4*)(a0 + o + mt * 16 * 384);
            const float4 x1 = *(const float4*)(a0 + o + mt * 16 * 384 + 4);
            union { bf16x8 v; unsigned u[4]; } ch, cl;
            ch.u[0] = pk2(x0.x, x0.y);
            ch.u[1] = pk2(x0.z, x0.w);
            ch.u[2] = pk2(x1.x, x1.y);
            ch.u[3] = pk2(x1.z, x1.w);
            cl.u[0] = pk2(x0.x - bflo(ch.u[0]), x0.y - bfhi(ch.u[0]));
            cl.u[1] = pk2(x0.z - bflo(ch.u[1]), x0.w - bfhi(ch.u[1]));
            cl.u[2] = pk2(x1.x - bflo(ch.u[2]), x1.y - bfhi(ch.u[2]));
            cl.u[3] = pk2(x1.z - bflo(ch.u[3]), x1.w - bfhi(ch.u[3]));
            ah[mt] = ch.v;
            al[mt] = cl.v;
        }

        #pragma unroll
        for (int nt = 0; nt < 2; ++nt) {
            const bf16x8 wh = *(const bf16x8*)(wfh + (nt * 12 + ks) * 512);
            const bf16x8 wl = *(const bf16x8*)(wfl + (nt * 12 + ks) * 512);
            #pragma unroll
            for (int mt = 0; mt < 2; ++mt) {
                acc[mt][nt] = __builtin_amdgcn_mfma_f32_16x16x32_bf16(
                    ah[mt], wh, acc[mt][nt], 0, 0, 0);
                acc[mt][nt] = __builtin_amdgcn_mfma_f32_16x16x32_bf16(
                    al[mt], wh, acc[mt][nt], 0, 0, 0);
                acc[mt][nt] = __builtin_amdgcn_mfma_f32_16x16x32_bf16(
                    ah[mt], wl, acc[mt][nt], 0, 0, 0);
            }
        }
    }

    if (z < 2) {
        const int* pos = z ? kpos : qpos;
        const float oscale = z ? 1.0f : 0.2082339551542919f;  // fold s2 into q
        const float invf = exp2f_fast(-(float)(l15 & 7) * 0.8304820237218405f)
                         * 0.15915494309189535f;   // 100^(-m/8) / 2pi
        const bool lo_half = (l15 < 8);
        #pragma unroll
        for (int nt = 0; nt < 2; ++nt) {
            const int c = n0 + nbl + nt * 16 + l15;
            const int h = div48(c);
            const int r0 = c - h * 48;
            const int axis = r0 >> 4;
            const float bb = bias[c];
            #pragma unroll
            for (int mt = 0; mt < 2; ++mt) {
                float a[4], pr[4];
                #pragma unroll
                for (int r = 0; r < 4; ++r) a[r] = acc[mt][nt][r] + bb;
                #pragma unroll
                for (int r = 0; r < 4; ++r) pr[r] = __shfl_xor(a[r], 8);
                #pragma unroll
                for (int r = 0; r < 4; ++r) {
                    const int t = mb + mt * 16 + quad * 4 + r;
                    const float pp = (float)pos[t * 3 + axis];
                    const float fr = ffract(pp * invf);
                    const float sn = fsin(fr), cn = fcos(fr);
                    const float o2 = lo_half ? (a[r] * cn - pr[r] * sn)
                                             : (a[r] * cn + pr[r] * sn);
                    const short val = f2bf(o2 * oscale);
                    const int b = t >> 11, n = t & 2047;
                    const int bh_ = b * 8 + h;
                    if (r0 < 32) {
                        short* pbuf = z ? kp0 : qp0;
                        pbuf[(((size_t)bh_ * 128 + (n >> 4)) * 64
                              + (r0 >> 3) * 16 + (n & 15)) * 8 + (r0 & 7)] = val;
                    } else if (z == 0) {
                        const int dd = r0 - 32;
                        qtb[(((size_t)bh_ * 128 + (n >> 4)) * 32
                             + (dd >> 3) * 16 + (n & 15)) * 8 + (dd & 7)] = val;
                    } else {
                        const int dd = r0 - 32;
                        ktb[(((size_t)bh_ * 64 + (n >> 5)) * 64
                             + ((n >> 4) & 1) * 32 + (dd >> 3) * 16 + (n & 15)) * 8
                            + (dd & 7)] = val;
                    }
                }
            }
        }
    } else {
        #pragma unroll
        for (int nt = 0; nt < 2; ++nt) {
            const int c = n0 + nbl + nt * 16 + l15;
            const int h = div48(c);
            const int r0 = c - h * 48;
            const float bb = bias[c];
            #pragma unroll
            for (int mt = 0; mt < 2; ++mt) {
                const int t0 = mb + mt * 16 + quad * 4;
                const int b = t0 >> 11, n = t0 & 2047;
                const int bh_ = b * 8 + h;
                s16x4 pk;
                #pragma unroll
                for (int r = 0; r < 4; ++r)
                    ((short*)&pk)[r] = f2bf(acc[mt][nt][r] + bb);
                // Vp: 4 consecutive n, same d -> j = n&7 in {0,4}: one 8B store
                const size_t off =
                    ((((size_t)bh_ * 16 + (n >> 7)) * 3 + (r0 >> 4)) * 4
                     + ((n >> 5) & 3)) * 512
                    + (((n >> 3) & 3) * 16 + (r0 & 15)) * 8 + (n & 7);
                *(s16x4*)(vp + off) = pk;
            }
        }
    }
}

// ---------------------------------------------------------------------------
// Output projection, 3-term split-bf16. LDS-free, fragment-major W, zero
// barriers. R16: occupancy fix — block tile 64m x 128n -> 16m x 128n
// (wave = 16m x 32n, acc[2]); grid 384 -> 1536 blocks (1.5 -> 6 blocks/CU).
// This kernel was the hidden ~55-60us cost: latency-bound at 1.5 blocks/CU,
// always just under the top-5 cutoff.
// ---------------------------------------------------------------------------
__global__ __launch_bounds__(256, 6)
void gemm_out(const short* __restrict__ xh, const short* __restrict__ xl,
              const short* __restrict__ Whp, const short* __restrict__ Wlp,
              const float* __restrict__ bo, float* __restrict__ out)
{
    const int tid = threadIdx.x;
    const int wv = tid >> 6, lane = tid & 63;
    const int l15 = lane & 15, quad = lane >> 4;
    const int mb = blockIdx.x * 16;
    const int nbl = wv * 32;
    const int n0 = blockIdx.y * 128;

    const int tbase = blockIdx.y * 8 + wv * 2 + 3 * 24;
    const short* wfh = Whp + ((size_t)tbase * 12 * 64 + lane) * 8;
    const short* wfl = Wlp + ((size_t)tbase * 12 * 64 + lane) * 8;

    f32x4 acc[2] = {};
    const short* a0 = xh + (size_t)(mb + l15) * 384 + quad * 8;
    const short* a1 = xl + (size_t)(mb + l15) * 384 + quad * 8;

    for (int ks = 0; ks < 12; ++ks) {
        const int o = ks * 32;
        const bf16x8 ah = *(const bf16x8*)(a0 + o);
        const bf16x8 al = *(const bf16x8*)(a1 + o);

        #pragma unroll
        for (int nt = 0; nt < 2; ++nt) {
            const bf16x8 wh = *(const bf16x8*)(wfh + (nt * 12 + ks) * 512);
            const bf16x8 wl = *(const bf16x8*)(wfl + (nt * 12 + ks) * 512);
            acc[nt] = __builtin_amdgcn_mfma_f32_16x16x32_bf16(
                ah, wh, acc[nt], 0, 0, 0);
            acc[nt] = __builtin_amdgcn_mfma_f32_16x16x32_bf16(
                al, wh, acc[nt], 0, 0, 0);
            acc[nt] = __builtin_amdgcn_mfma_f32_16x16x32_bf16(
                ah, wl, acc[nt], 0, 0, 0);
        }
    }

    #pragma unroll
    for (int nt = 0; nt < 2; ++nt) {
        const int c = n0 + nbl + nt * 16 + l15;
        const float bb = bo[c];
        #pragma unroll
        for (int r = 0; r < 4; ++r)
            out[(size_t)(mb + quad * 4 + r) * 384 + c] = acc[nt][r] + bb;
    }
}

// ---------------------------------------------------------------------------
// Flash attention (R15 structure, measured best 60.8us): cooperative LDS
// staging of the 24KB K/V tile (each wave stages a quarter; VMEM port
// traffic 4x lower), register prefetch of next kt's quarter, setprio around
// MFMA clusters, no running max (q pre-scaled), 4-way parallel l acc,
// XCD-swizzled bh. LDS 24KB Stg + 17.4KB Ps -> 3 blocks/CU.
// ---------------------------------------------------------------------------
__global__ __launch_bounds__(256, 3)
void attn_mfma(const short* __restrict__ Qp0, const short* __restrict__ Qt,
               const short* __restrict__ Kp0, const short* __restrict__ Kt,
               const short* __restrict__ Vp,
               short* __restrict__ x2h, short* __restrict__ x2l)
{
    __shared__ short Stg[24 * 512];    // staged K/V tile: 24 frags x 1KB
    __shared__ short Ps[4][16][136];   // [wave][q][kv 0..127], stride 272 B
    const int tid = threadIdx.x;
    const int wave = tid >> 6;
    const int lane = tid & 63;
    const int l15 = lane & 15;
    const int quad = lane >> 4;
    const int L = blockIdx.x;
    const int bh = (L & 7) + ((L >> 8) << 3);
    const int q0 = ((L >> 3) & 31) << 6;

    // Q fragments (contiguous loads)
    const int qt16 = (q0 >> 4) + wave;
    const bf16x8 qb0 = *(const bf16x8*)
        (Qp0 + (((size_t)bh * 128 + qt16) * 64 + lane) * 8);
    const bf16x8 qtl = *(const bf16x8*)
        (Qt + (((size_t)bh * 128 + qt16) * 32 + (lane & 31)) * 8);
    const bf16x8 z8 = {0, 0, 0, 0, 0, 0, 0, 0};
    const bf16x8 qb1lo = (quad < 2) ? qtl : z8;
    const bf16x8 qb1hi = (quad < 2) ? z8 : qtl;

    f32x4 of[3];
    #pragma unroll
    for (int t = 0; t < 3; ++t) of[t] = (f32x4){0.f, 0.f, 0.f, 0.f};
    f32x4 lsv = (f32x4){0.f, 0.f, 0.f, 0.f};

    const int fbase = wave * 6;        // this wave's 6 staged fragments

    // ---- prologue: prefetch kt=0 quarter into regs ----
    bf16x8 rs[6];
    #pragma unroll
    for (int i = 0; i < 6; ++i) {
        const int f = fbase + i;
        const short* src;
        if (f < 8)
            src = Kp0 + (((size_t)bh * 128 + f) * 64 + lane) * 8;
        else if (f < 12)
            src = Kt + (((size_t)bh * 64 + (f - 8)) * 64 + lane) * 8;
        else
            src = Vp + ((((size_t)bh * 16) * 12 + (f - 12)) * 64 + lane) * 8;
        rs[i] = *(const bf16x8*)src;
    }

    for (int kt = 0; kt < 16; ++kt) {
        // ---- stage: previous readers done -> write this kt's quarter ----
        __syncthreads();
        #pragma unroll
        for (int i = 0; i < 6; ++i)
            *(bf16x8*)&Stg[(fbase + i) * 512 + lane * 8] = rs[i];
        __syncthreads();

        // ---- issue next-kt quarter loads; latency hides under compute ----
        if (kt < 15) {
            #pragma unroll
            for (int i = 0; i < 6; ++i) {
                const int f = fbase + i;
                const short* src;
                if (f < 8)
                    src = Kp0 + (((size_t)bh * 128 + (kt + 1) * 8 + f) * 64 + lane) * 8;
                else if (f < 12)
                    src = Kt + (((size_t)bh * 64 + (kt + 1) * 4 + (f - 8)) * 64 + lane) * 8;
                else
                    src = Vp + ((((size_t)bh * 16 + kt + 1) * 12 + (f - 12)) * 64 + lane) * 8;
                rs[i] = *(const bf16x8*)src;
            }
        }

        // ---- S^T = K Q^T : K fragments from LDS ----
        f32x4 sf[8];
        __builtin_amdgcn_s_setprio(1);
        #pragma unroll
        for (int p = 0; p < 4; ++p) {
            const bf16x8 ka0 = *(const bf16x8*)&Stg[(2 * p) * 512 + lane * 8];
            const bf16x8 ka1 = *(const bf16x8*)&Stg[(2 * p + 1) * 512 + lane * 8];
            const bf16x8 kts = *(const bf16x8*)&Stg[(8 + p) * 512 + lane * 8];
            f32x4 z0 = (f32x4){0.f, 0.f, 0.f, 0.f};
            z0 = __builtin_amdgcn_mfma_f32_16x16x32_bf16(ka0, qb0, z0, 0, 0, 0);
            sf[2 * p] = __builtin_amdgcn_mfma_f32_16x16x32_bf16(kts, qb1lo, z0, 0, 0, 0);
            f32x4 z1 = (f32x4){0.f, 0.f, 0.f, 0.f};
            z1 = __builtin_amdgcn_mfma_f32_16x16x32_bf16(ka1, qb0, z1, 0, 0, 0);
            sf[2 * p + 1] = __builtin_amdgcn_mfma_f32_16x16x32_bf16(kts, qb1hi, z1, 0, 0, 0);
        }
        __builtin_amdgcn_s_setprio(0);

        // ---- p = exp2(sf); row-sum (4 parallel accs); pack to LDS strip ----
        #pragma unroll
        for (int t = 0; t < 8; ++t) {
            const float p0 = exp2f_fast(sf[t][0]);
            const float p1 = exp2f_fast(sf[t][1]);
            const float p2 = exp2f_fast(sf[t][2]);
            const float p3 = exp2f_fast(sf[t][3]);
            lsv[0] += p0; lsv[1] += p1; lsv[2] += p2; lsv[3] += p3;
            uint2 w;
            w.x = pk_bf16(p0, p1);
            w.y = pk_bf16(p2, p3);
            *(uint2*)&Ps[wave][l15][t * 16 + quad * 4] = w;
        }

        // ---- O^T += V^T P^T : V fragments from LDS ----
        bf16x8 pb[4];
        #pragma unroll
        for (int s = 0; s < 4; ++s)
            pb[s] = *(const bf16x8*)&Ps[wave][l15][s * 32 + quad * 8];
        __builtin_amdgcn_s_setprio(1);
        #pragma unroll
        for (int t = 0; t < 3; ++t) {
            #pragma unroll
            for (int s = 0; s < 4; ++s) {
                const bf16x8 va = *(const bf16x8*)&Stg[(12 + t * 4 + s) * 512 + lane * 8];
                of[t] = __builtin_amdgcn_mfma_f32_16x16x32_bf16(
                    va, pb[s], of[t], 0, 0, 0);
            }
        }
        __builtin_amdgcn_s_setprio(0);
    }

    // ---- reduce l; normalize; split hi/lo write ----
    float ls = (lsv[0] + lsv[1]) + (lsv[2] + lsv[3]);
    ls += __shfl_xor(ls, 16);
    ls += __shfl_xor(ls, 32);
    const float invl = 1.0f / ls;
    const int b = bh >> 3, h = bh & 7;
    const size_t off = (size_t)(b * 2048 + q0 + wave * 16 + l15) * 384
                     + h * 48 + quad * 4;
    #pragma unroll
    for (int t = 0; t < 3; ++t) {
        const float o0 = of[t][0] * invl;
        const float o1 = of[t][1] * invl;
        const float o2 = of[t][2] * invl;
        const float o3 = of[t][3] * invl;
        const unsigned h01 = pk_bf16(o0, o1);
        const unsigned h23 = pk_bf16(o2, o3);
        uint2 hv; hv.x = h01; hv.y = h23;
        uint2 lv;
        lv.x = pk2(o0 - bflo(h01), o1 - bfhi(h01));
        lv.y = pk2(o2 - bflo(h23), o3 - bfhi(h23));
        *(uint2*)(x2h + off + t * 16) = hv;
        *(uint2*)(x2l + off + t * 16) = lv;
    }
}

// ---------------------------------------------------------------------------
extern "C" void kernel_launch(void* const* d_in, const int* in_sizes, int n_in,
                              void* d_out, int out_size, void* d_ws, size_t ws_size,
                              hipStream_t stream)
{
    const float* query = (const float*)d_in[0];
    const float* key_  = (const float*)d_in[1];
    const float* value = (const float*)d_in[2];
    const float* Wq = (const float*)d_in[3];
    const float* bq = (const float*)d_in[4];
    const float* Wk = (const float*)d_in[5];
    const float* bk = (const float*)d_in[6];
    const float* Wv = (const float*)d_in[7];
    const float* bv = (const float*)d_in[8];
    const float* Wo = (const float*)d_in[9];
    const float* bo = (const float*)d_in[10];
    const int* qpos = (const int*)d_in[11];
    const int* kpos = (const int*)d_in[12];

    // Workspace (shorts). Total ~33.8 MB; harness evidence: ws >= 45.1 MB.
    const size_t QP0_S = (size_t)32 * 128 * 64 * 8;   // 2,097,152
    const size_t QT_S  = (size_t)32 * 128 * 32 * 8;   // 1,048,576
    const size_t KP0_S = QP0_S;
    const size_t KT_S  = (size_t)32 * 64 * 64 * 8;    // 1,048,576
    const size_t VP_S  = (size_t)32 * 16 * 12 * 64 * 8; // 3,145,728
    const size_t X2_S  = (size_t)8192 * 384;          // 3,145,728
    const size_t W_S   = (size_t)4 * 384 * 384;       // 589,824

    short* w = (short*)d_ws;
    short* qp0 = w;  w += QP0_S;
    short* qtb = w;  w += QT_S;
    short* kp0 = w;  w += KP0_S;
    short* ktb = w;  w += KT_S;
    short* vp  = w;  w += VP_S;
    short* x2h = w;  w += X2_S;
    short* x2l = w;  w += X2_S;
    short* Wh  = w;  w += W_S;
    short* Wl  = w;

    const dim3 blk(256);
    cvt_w<<<dim3(144, 4), blk, 0, stream>>>(Wq, Wk, Wv, Wo, Wh, Wl);
    gemm_qkv<<<dim3(256, 3, 3), blk, 0, stream>>>(
        query, key_, value, Wh, Wl, bq, bk, bv, qpos, kpos,
        qp0, qtb, kp0, ktb, vp);
    attn_mfma<<<dim3(1024), blk, 0, stream>>>(qp0, qtb, kp0, ktb, vp, x2h, x2l);
    gemm_out<<<dim3(512, 3), blk, 0, stream>>>(x2h, x2l, Wh, Wl, bo,
                                               (float*)d_out);
}

// Round 9
// 228.486 us; speedup vs baseline: 1.1043x; 1.1043x over previous
//
#include <hip/hip_runtime.h>
#include <hip/hip_bf16.h>
#include <math.h>

// B=4, N=2048, C=384, H=8, HD=48, T=8192. scale=1/sqrt(48). RoPE base 100.

typedef __attribute__((ext_vector_type(8))) short bf16x8;
typedef __attribute__((ext_vector_type(4))) float f32x4;
typedef __attribute__((ext_vector_type(4))) short s16x4;

// RNE bf16 (scalar, 3 ops)
__device__ inline short f2bf(float f) {
    unsigned u = __float_as_uint(f);
    u += 0x7fffu + ((u >> 16) & 1u);
    return (short)(u >> 16);
}
// HW packed RNE cvt (1 op): bf16(a) | bf16(b)<<16
__device__ inline unsigned pk_bf16(float a, float b) {
    __hip_bfloat162 h = __float22bfloat162_rn(make_float2(a, b));
    return *(reinterpret_cast<unsigned*>(&h));
}
// truncation packs (for hi/lo splits; remainder carried exactly in lo)
__device__ inline unsigned pk2(float lo, float hi) {
    return (__float_as_uint(lo) >> 16) | (__float_as_uint(hi) & 0xffff0000u);
}
__device__ inline float bflo(unsigned u) { return __uint_as_float(u << 16); }
__device__ inline float bfhi(unsigned u) { return __uint_as_float(u & 0xffff0000u); }
__device__ inline float exp2f_fast(float x) {
#if __has_builtin(__builtin_amdgcn_exp2f)
    return __builtin_amdgcn_exp2f(x);
#else
    return exp2f(x);
#endif
}
__device__ inline float ffract(float x) {
    float r;
    asm("v_fract_f32 %0, %1" : "=v"(r) : "v"(x));
    return r;
}
__device__ inline float fsin(float x) {   // x in revolutions, pre-reduced
    float r;
    asm("v_sin_f32 %0, %1\n\ts_nop 1" : "=v"(r) : "v"(x));
    return r;
}
__device__ inline float fcos(float x) {
    float r;
    asm("v_cos_f32 %0, %1\n\ts_nop 1" : "=v"(r) : "v"(x));
    return r;
}
__device__ inline int div48(int c) { return (c * 683) >> 15; }

// ---------------------------------------------------------------------------
// Weights fp32 -> hi/lo bf16 planes in MFMA B-FRAGMENT-MAJOR order:
//   Wf[z][tile=c>>4][ks=k>>5][lane=((k>>3)&3)*16 + (c&15)][j=k&7]
// so a wave's B fragment for (tile,ks) is ONE contiguous 1KB load.
// Wq,Wk,Wv,Wo concatenated (147456 shorts each).
// ---------------------------------------------------------------------------
__global__ __launch_bounds__(256)
void cvt_w(const float* __restrict__ w0, const float* __restrict__ w1,
           const float* __restrict__ w2, const float* __restrict__ w3,
           short* __restrict__ Wh, short* __restrict__ Wl)
{
    const float* s = blockIdx.y == 0 ? w0 : blockIdx.y == 1 ? w1
                   : blockIdx.y == 2 ? w2 : w3;
    const size_t i = (size_t)(blockIdx.x * 256 + threadIdx.x) * 4;
    const int c = (int)(i / 384);        // out-feature row
    const int k = (int)(i % 384);        // k%4==0 -> all 4 elems same quad/j-run
    const float4 x = *(const float4*)(s + i);
    const unsigned h01 = pk2(x.x, x.y);
    const unsigned h23 = pk2(x.z, x.w);
    const unsigned l01 = pk2(x.x - bflo(h01), x.y - bfhi(h01));
    const unsigned l23 = pk2(x.z - bflo(h23), x.w - bfhi(h23));
    // fragment-major dest (j = k&7 in {0,4}: 4 consecutive shorts = 8B store)
    const size_t off =
        ((((size_t)blockIdx.y * 24 + (c >> 4)) * 12 + (k >> 5)) * 64
         + ((k >> 3) & 3) * 16 + (c & 15)) * 8 + (k & 7);
    uint2 hv; hv.x = h01; hv.y = h23;
    uint2 lv; lv.x = l01; lv.y = l23;
    *(uint2*)(Wh + off) = hv;
    *(uint2*)(Wl + off) = lv;
}

// ---------------------------------------------------------------------------
// Fused QKV projection, 3-term split-bf16 MFMA. LDS-free, fragment-major W,
// zero barriers (R12-proven core, 64m x 128n tile — R16's 32m shrink
// REVERTED: halved per-wave MFMA with same load chain -> 86us regression).
// R17: explicit depth-2 register pipeline on A — ks+1's four float4 loads
// issue before ks's cvt+MFMA body (full-iteration dependency distance, the
// mechanism that won in attn R11). +32 VGPR, under the 4-waves/SIMD cap.
// Epilogues write FRAGMENT-MAJOR packed buffers (see attn).
// q pre-scaled by s2 = scale*log2(e) so attn exp2 takes raw S.
// ---------------------------------------------------------------------------
__global__ __launch_bounds__(256, 4)
void gemm_qkv(const float* __restrict__ q_in, const float* __restrict__ k_in,
              const float* __restrict__ v_in,
              const short* __restrict__ Whp, const short* __restrict__ Wlp,
              const float* __restrict__ bq, const float* __restrict__ bk,
              const float* __restrict__ bv,
              const int* __restrict__ qpos, const int* __restrict__ kpos,
              short* __restrict__ qp0, short* __restrict__ qtb,
              short* __restrict__ kp0, short* __restrict__ ktb,
              short* __restrict__ vp)
{
    const int z = blockIdx.z;
    const float* A = z == 0 ? q_in : z == 1 ? k_in : v_in;
    const float* bias = z == 0 ? bq : z == 1 ? bk : bv;

    const int tid = threadIdx.x;
    const int wv = tid >> 6, lane = tid & 63;
    const int l15 = lane & 15, quad = lane >> 4;
    const int mb = blockIdx.x * 64 + (wv & 1) * 32;
    const int nbl = (wv >> 1) * 64;
    const int n0 = blockIdx.y * 128;

    // fragment-major W base for this wave's 4 n-tiles
    const int tbase = blockIdx.y * 8 + (wv >> 1) * 4 + z * 24;
    const short* wfh = Whp + ((size_t)tbase * 12 * 64 + lane) * 8;
    const short* wfl = Wlp + ((size_t)tbase * 12 * 64 + lane) * 8;

    f32x4 acc[2][4] = {};
    const float* a0 = A + (size_t)(mb + l15) * 384 + quad * 8;

    // ---- prologue: prefetch ks=0 A into named registers ----
    float4 nx0[2], nx1[2];
    #pragma unroll
    for (int mt = 0; mt < 2; ++mt) {
        nx0[mt] = *(const float4*)(a0 + mt * 16 * 384);
        nx1[mt] = *(const float4*)(a0 + mt * 16 * 384 + 4);
    }

    for (int ks = 0; ks < 12; ++ks) {
        const int o = ks * 32;
        // consume prefetched A
        float4 cx0[2], cx1[2];
        #pragma unroll
        for (int mt = 0; mt < 2; ++mt) { cx0[mt] = nx0[mt]; cx1[mt] = nx1[mt]; }
        // issue ks+1 loads: full iteration of cvt+MFMA hides their latency
        if (ks < 11) {
            #pragma unroll
            for (int mt = 0; mt < 2; ++mt) {
                nx0[mt] = *(const float4*)(a0 + o + 32 + mt * 16 * 384);
                nx1[mt] = *(const float4*)(a0 + o + 32 + mt * 16 * 384 + 4);
            }
        }

        bf16x8 ah[2], al[2];
        #pragma unroll
        for (int mt = 0; mt < 2; ++mt) {
            union { bf16x8 v; unsigned u[4]; } ch, cl;
            ch.u[0] = pk2(cx0[mt].x, cx0[mt].y);
            ch.u[1] = pk2(cx0[mt].z, cx0[mt].w);
            ch.u[2] = pk2(cx1[mt].x, cx1[mt].y);
            ch.u[3] = pk2(cx1[mt].z, cx1[mt].w);
            cl.u[0] = pk2(cx0[mt].x - bflo(ch.u[0]), cx0[mt].y - bfhi(ch.u[0]));
            cl.u[1] = pk2(cx0[mt].z - bflo(ch.u[1]), cx0[mt].w - bfhi(ch.u[1]));
            cl.u[2] = pk2(cx1[mt].x - bflo(ch.u[2]), cx1[mt].y - bfhi(ch.u[2]));
            cl.u[3] = pk2(cx1[mt].z - bflo(ch.u[3]), cx1[mt].w - bfhi(ch.u[3]));
            ah[mt] = ch.v;
            al[mt] = cl.v;
        }

        #pragma unroll
        for (int nt = 0; nt < 4; ++nt) {
            const bf16x8 wh = *(const bf16x8*)(wfh + (nt * 12 + ks) * 512);
            const bf16x8 wl = *(const bf16x8*)(wfl + (nt * 12 + ks) * 512);
            #pragma unroll
            for (int mt = 0; mt < 2; ++mt) {
                acc[mt][nt] = __builtin_amdgcn_mfma_f32_16x16x32_bf16(
                    ah[mt], wh, acc[mt][nt], 0, 0, 0);
                acc[mt][nt] = __builtin_amdgcn_mfma_f32_16x16x32_bf16(
                    al[mt], wh, acc[mt][nt], 0, 0, 0);
                acc[mt][nt] = __builtin_amdgcn_mfma_f32_16x16x32_bf16(
                    ah[mt], wl, acc[mt][nt], 0, 0, 0);
            }
        }
    }

    if (z < 2) {
        const int* pos = z ? kpos : qpos;
        const float oscale = z ? 1.0f : 0.2082339551542919f;  // fold s2 into q
        const float invf = exp2f_fast(-(float)(l15 & 7) * 0.8304820237218405f)
                         * 0.15915494309189535f;   // 100^(-m/8) / 2pi
        const bool lo_half = (l15 < 8);
        #pragma unroll
        for (int nt = 0; nt < 4; ++nt) {
            const int c = n0 + nbl + nt * 16 + l15;
            const int h = div48(c);
            const int r0 = c - h * 48;
            const int axis = r0 >> 4;
            const float bb = bias[c];
            #pragma unroll
            for (int mt = 0; mt < 2; ++mt) {
                float a[4], pr[4];
                #pragma unroll
                for (int r = 0; r < 4; ++r) a[r] = acc[mt][nt][r] + bb;
                #pragma unroll
                for (int r = 0; r < 4; ++r) pr[r] = __shfl_xor(a[r], 8);
                #pragma unroll
                for (int r = 0; r < 4; ++r) {
                    const int t = mb + mt * 16 + quad * 4 + r;
                    const float pp = (float)pos[t * 3 + axis];
                    const float fr = ffract(pp * invf);
                    const float sn = fsin(fr), cn = fcos(fr);
                    const float o2 = lo_half ? (a[r] * cn - pr[r] * sn)
                                             : (a[r] * cn + pr[r] * sn);
                    const short val = f2bf(o2 * oscale);
                    const int b = t >> 11, n = t & 2047;
                    const int bh_ = b * 8 + h;
                    if (r0 < 32) {
                        short* pbuf = z ? kp0 : qp0;
                        pbuf[(((size_t)bh_ * 128 + (n >> 4)) * 64
                              + (r0 >> 3) * 16 + (n & 15)) * 8 + (r0 & 7)] = val;
                    } else if (z == 0) {
                        const int dd = r0 - 32;
                        qtb[(((size_t)bh_ * 128 + (n >> 4)) * 32
                             + (dd >> 3) * 16 + (n & 15)) * 8 + (dd & 7)] = val;
                    } else {
                        const int dd = r0 - 32;
                        ktb[(((size_t)bh_ * 64 + (n >> 5)) * 64
                             + ((n >> 4) & 1) * 32 + (dd >> 3) * 16 + (n & 15)) * 8
                            + (dd & 7)] = val;
                    }
                }
            }
        }
    } else {
        #pragma unroll
        for (int nt = 0; nt < 4; ++nt) {
            const int c = n0 + nbl + nt * 16 + l15;
            const int h = div48(c);
            const int r0 = c - h * 48;
            const float bb = bias[c];
            #pragma unroll
            for (int mt = 0; mt < 2; ++mt) {
                const int t0 = mb + mt * 16 + quad * 4;
                const int b = t0 >> 11, n = t0 & 2047;
                const int bh_ = b * 8 + h;
                s16x4 pk;
                #pragma unroll
                for (int r = 0; r < 4; ++r)
                    ((short*)&pk)[r] = f2bf(acc[mt][nt][r] + bb);
                // Vp: 4 consecutive n, same d -> j = n&7 in {0,4}: one 8B store
                const size_t off =
                    ((((size_t)bh_ * 16 + (n >> 7)) * 3 + (r0 >> 4)) * 4
                     + ((n >> 5) & 3)) * 512
                    + (((n >> 3) & 3) * 16 + (r0 & 15)) * 8 + (n & 7);
                *(s16x4*)(vp + off) = pk;
            }
        }
    }
}

// ---------------------------------------------------------------------------
// Output projection, 3-term split-bf16. LDS-free, fragment-major W, zero
// barriers. R16 tile kept (16m x 128n, 1536 blocks, 6 blocks/CU) so this
// round gives a clean read on whether the out fix was real. R17: depth-2
// register pipeline on the x2 loads (+8 VGPR).
// ---------------------------------------------------------------------------
__global__ __launch_bounds__(256, 6)
void gemm_out(const short* __restrict__ xh, const short* __restrict__ xl,
              const short* __restrict__ Whp, const short* __restrict__ Wlp,
              const float* __restrict__ bo, float* __restrict__ out)
{
    const int tid = threadIdx.x;
    const int wv = tid >> 6, lane = tid & 63;
    const int l15 = lane & 15, quad = lane >> 4;
    const int mb = blockIdx.x * 16;
    const int nbl = wv * 32;
    const int n0 = blockIdx.y * 128;

    const int tbase = blockIdx.y * 8 + wv * 2 + 3 * 24;
    const short* wfh = Whp + ((size_t)tbase * 12 * 64 + lane) * 8;
    const short* wfl = Wlp + ((size_t)tbase * 12 * 64 + lane) * 8;

    f32x4 acc[2] = {};
    const short* a0 = xh + (size_t)(mb + l15) * 384 + quad * 8;
    const short* a1 = xl + (size_t)(mb + l15) * 384 + quad * 8;

    bf16x8 nah = *(const bf16x8*)(a0);
    bf16x8 nal = *(const bf16x8*)(a1);

    for (int ks = 0; ks < 12; ++ks) {
        const int o = ks * 32;
        const bf16x8 ah = nah;
        const bf16x8 al = nal;
        if (ks < 11) {
            nah = *(const bf16x8*)(a0 + o + 32);
            nal = *(const bf16x8*)(a1 + o + 32);
        }

        #pragma unroll
        for (int nt = 0; nt < 2; ++nt) {
            const bf16x8 wh = *(const bf16x8*)(wfh + (nt * 12 + ks) * 512);
            const bf16x8 wl = *(const bf16x8*)(wfl + (nt * 12 + ks) * 512);
            acc[nt] = __builtin_amdgcn_mfma_f32_16x16x32_bf16(
                ah, wh, acc[nt], 0, 0, 0);
            acc[nt] = __builtin_amdgcn_mfma_f32_16x16x32_bf16(
                al, wh, acc[nt], 0, 0, 0);
            acc[nt] = __builtin_amdgcn_mfma_f32_16x16x32_bf16(
                ah, wl, acc[nt], 0, 0, 0);
        }
    }

    #pragma unroll
    for (int nt = 0; nt < 2; ++nt) {
        const int c = n0 + nbl + nt * 16 + l15;
        const float bb = bo[c];
        #pragma unroll
        for (int r = 0; r < 4; ++r)
            out[(size_t)(mb + quad * 4 + r) * 384 + c] = acc[nt][r] + bb;
    }
}

// ---------------------------------------------------------------------------
// Flash attention (R15 structure, measured best 60.8us): cooperative LDS
// staging of the 24KB K/V tile (each wave stages a quarter; VMEM port
// traffic 4x lower), register prefetch of next kt's quarter, setprio around
// MFMA clusters, no running max (q pre-scaled), 4-way parallel l acc,
// XCD-swizzled bh. LDS 24KB Stg + 17.4KB Ps -> 3 blocks/CU.
// ---------------------------------------------------------------------------
__global__ __launch_bounds__(256, 3)
void attn_mfma(const short* __restrict__ Qp0, const short* __restrict__ Qt,
               const short* __restrict__ Kp0, const short* __restrict__ Kt,
               const short* __restrict__ Vp,
               short* __restrict__ x2h, short* __restrict__ x2l)
{
    __shared__ short Stg[24 * 512];    // staged K/V tile: 24 frags x 1KB
    __shared__ short Ps[4][16][136];   // [wave][q][kv 0..127], stride 272 B
    const int tid = threadIdx.x;
    const int wave = tid >> 6;
    const int lane = tid & 63;
    const int l15 = lane & 15;
    const int quad = lane >> 4;
    const int L = blockIdx.x;
    const int bh = (L & 7) + ((L >> 8) << 3);
    const int q0 = ((L >> 3) & 31) << 6;

    // Q fragments (contiguous loads)
    const int qt16 = (q0 >> 4) + wave;
    const bf16x8 qb0 = *(const bf16x8*)
        (Qp0 + (((size_t)bh * 128 + qt16) * 64 + lane) * 8);
    const bf16x8 qtl = *(const bf16x8*)
        (Qt + (((size_t)bh * 128 + qt16) * 32 + (lane & 31)) * 8);
    const bf16x8 z8 = {0, 0, 0, 0, 0, 0, 0, 0};
    const bf16x8 qb1lo = (quad < 2) ? qtl : z8;
    const bf16x8 qb1hi = (quad < 2) ? z8 : qtl;

    f32x4 of[3];
    #pragma unroll
    for (int t = 0; t < 3; ++t) of[t] = (f32x4){0.f, 0.f, 0.f, 0.f};
    f32x4 lsv = (f32x4){0.f, 0.f, 0.f, 0.f};

    const int fbase = wave * 6;        // this wave's 6 staged fragments

    // ---- prologue: prefetch kt=0 quarter into regs ----
    bf16x8 rs[6];
    #pragma unroll
    for (int i = 0; i < 6; ++i) {
        const int f = fbase + i;
        const short* src;
        if (f < 8)
            src = Kp0 + (((size_t)bh * 128 + f) * 64 + lane) * 8;
        else if (f < 12)
            src = Kt + (((size_t)bh * 64 + (f - 8)) * 64 + lane) * 8;
        else
            src = Vp + ((((size_t)bh * 16) * 12 + (f - 12)) * 64 + lane) * 8;
        rs[i] = *(const bf16x8*)src;
    }

    for (int kt = 0; kt < 16; ++kt) {
        // ---- stage: previous readers done -> write this kt's quarter ----
        __syncthreads();
        #pragma unroll
        for (int i = 0; i < 6; ++i)
            *(bf16x8*)&Stg[(fbase + i) * 512 + lane * 8] = rs[i];
        __syncthreads();

        // ---- issue next-kt quarter loads; latency hides under compute ----
        if (kt < 15) {
            #pragma unroll
            for (int i = 0; i < 6; ++i) {
                const int f = fbase + i;
                const short* src;
                if (f < 8)
                    src = Kp0 + (((size_t)bh * 128 + (kt + 1) * 8 + f) * 64 + lane) * 8;
                else if (f < 12)
                    src = Kt + (((size_t)bh * 64 + (kt + 1) * 4 + (f - 8)) * 64 + lane) * 8;
                else
                    src = Vp + ((((size_t)bh * 16 + kt + 1) * 12 + (f - 12)) * 64 + lane) * 8;
                rs[i] = *(const bf16x8*)src;
            }
        }

        // ---- S^T = K Q^T : K fragments from LDS ----
        f32x4 sf[8];
        __builtin_amdgcn_s_setprio(1);
        #pragma unroll
        for (int p = 0; p < 4; ++p) {
            const bf16x8 ka0 = *(const bf16x8*)&Stg[(2 * p) * 512 + lane * 8];
            const bf16x8 ka1 = *(const bf16x8*)&Stg[(2 * p + 1) * 512 + lane * 8];
            const bf16x8 kts = *(const bf16x8*)&Stg[(8 + p) * 512 + lane * 8];
            f32x4 z0 = (f32x4){0.f, 0.f, 0.f, 0.f};
            z0 = __builtin_amdgcn_mfma_f32_16x16x32_bf16(ka0, qb0, z0, 0, 0, 0);
            sf[2 * p] = __builtin_amdgcn_mfma_f32_16x16x32_bf16(kts, qb1lo, z0, 0, 0, 0);
            f32x4 z1 = (f32x4){0.f, 0.f, 0.f, 0.f};
            z1 = __builtin_amdgcn_mfma_f32_16x16x32_bf16(ka1, qb0, z1, 0, 0, 0);
            sf[2 * p + 1] = __builtin_amdgcn_mfma_f32_16x16x32_bf16(kts, qb1hi, z1, 0, 0, 0);
        }
        __builtin_amdgcn_s_setprio(0);

        // ---- p = exp2(sf); row-sum (4 parallel accs); pack to LDS strip ----
        #pragma unroll
        for (int t = 0; t < 8; ++t) {
            const float p0 = exp2f_fast(sf[t][0]);
            const float p1 = exp2f_fast(sf[t][1]);
            const float p2 = exp2f_fast(sf[t][2]);
            const float p3 = exp2f_fast(sf[t][3]);
            lsv[0] += p0; lsv[1] += p1; lsv[2] += p2; lsv[3] += p3;
            uint2 w;
            w.x = pk_bf16(p0, p1);
            w.y = pk_bf16(p2, p3);
            *(uint2*)&Ps[wave][l15][t * 16 + quad * 4] = w;
        }

        // ---- O^T += V^T P^T : V fragments from LDS ----
        bf16x8 pb[4];
        #pragma unroll
        for (int s = 0; s < 4; ++s)
            pb[s] = *(const bf16x8*)&Ps[wave][l15][s * 32 + quad * 8];
        __builtin_amdgcn_s_setprio(1);
        #pragma unroll
        for (int t = 0; t < 3; ++t) {
            #pragma unroll
            for (int s = 0; s < 4; ++s) {
                const bf16x8 va = *(const bf16x8*)&Stg[(12 + t * 4 + s) * 512 + lane * 8];
                of[t] = __builtin_amdgcn_mfma_f32_16x16x32_bf16(
                    va, pb[s], of[t], 0, 0, 0);
            }
        }
        __builtin_amdgcn_s_setprio(0);
    }

    // ---- reduce l; normalize; split hi/lo write ----
    float ls = (lsv[0] + lsv[1]) + (lsv[2] + lsv[3]);
    ls += __shfl_xor(ls, 16);
    ls += __shfl_xor(ls, 32);
    const float invl = 1.0f / ls;
    const int b = bh >> 3, h = bh & 7;
    const size_t off = (size_t)(b * 2048 + q0 + wave * 16 + l15) * 384
                     + h * 48 + quad * 4;
    #pragma unroll
    for (int t = 0; t < 3; ++t) {
        const float o0 = of[t][0] * invl;
        const float o1 = of[t][1] * invl;
        const float o2 = of[t][2] * invl;
        const float o3 = of[t][3] * invl;
        const unsigned h01 = pk_bf16(o0, o1);
        const unsigned h23 = pk_bf16(o2, o3);
        uint2 hv; hv.x = h01; hv.y = h23;
        uint2 lv;
        lv.x = pk2(o0 - bflo(h01), o1 - bfhi(h01));
        lv.y = pk2(o2 - bflo(h23), o3 - bfhi(h23));
        *(uint2*)(x2h + off + t * 16) = hv;
        *(uint2*)(x2l + off + t * 16) = lv;
    }
}

// ---------------------------------------------------------------------------
extern "C" void kernel_launch(void* const* d_in, const int* in_sizes, int n_in,
                              void* d_out, int out_size, void* d_ws, size_t ws_size,
                              hipStream_t stream)
{
    const float* query = (const float*)d_in[0];
    const float* key_  = (const float*)d_in[1];
    const float* value = (const float*)d_in[2];
    const float* Wq = (const float*)d_in[3];
    const float* bq = (const float*)d_in[4];
    const float* Wk = (const float*)d_in[5];
    const float* bk = (const float*)d_in[6];
    const float* Wv = (const float*)d_in[7];
    const float* bv = (const float*)d_in[8];
    const float* Wo = (const float*)d_in[9];
    const float* bo = (const float*)d_in[10];
    const int* qpos = (const int*)d_in[11];
    const int* kpos = (const int*)d_in[12];

    // Workspace (shorts). Total ~33.8 MB; harness evidence: ws >= 45.1 MB.
    const size_t QP0_S = (size_t)32 * 128 * 64 * 8;   // 2,097,152
    const size_t QT_S  = (size_t)32 * 128 * 32 * 8;   // 1,048,576
    const size_t KP0_S = QP0_S;
    const size_t KT_S  = (size_t)32 * 64 * 64 * 8;    // 1,048,576
    const size_t VP_S  = (size_t)32 * 16 * 12 * 64 * 8; // 3,145,728
    const size_t X2_S  = (size_t)8192 * 384;          // 3,145,728
    const size_t W_S   = (size_t)4 * 384 * 384;       // 589,824

    short* w = (short*)d_ws;
    short* qp0 = w;  w += QP0_S;
    short* qtb = w;  w += QT_S;
    short* kp0 = w;  w += KP0_S;
    short* ktb = w;  w += KT_S;
    short* vp  = w;  w += VP_S;
    short* x2h = w;  w += X2_S;
    short* x2l = w;  w += X2_S;
    short* Wh  = w;  w += W_S;
    short* Wl  = w;

    const dim3 blk(256);
    cvt_w<<<dim3(144, 4), blk, 0, stream>>>(Wq, Wk, Wv, Wo, Wh, Wl);
    gemm_qkv<<<dim3(128, 3, 3), blk, 0, stream>>>(
        query, key_, value, Wh, Wl, bq, bk, bv, qpos, kpos,
        qp0, qtb, kp0, ktb, vp);
    attn_mfma<<<dim3(1024), blk, 0, stream>>>(qp0, qtb, kp0, ktb, vp, x2h, x2l);
    gemm_out<<<dim3(512, 3), blk, 0, stream>>>(x2h, x2l, Wh, Wl, bo,
                                               (float*)d_out);
}